// Round 4
// baseline (38.276 us; speedup 1.0000x reference)
//
#include <hip/hip_runtime.h>
#include <math.h>

#define BB 512
#define DD 256
#define TMARGIN 0.2f
#define NBLK 256          // 2 anchors per block
#define NTHR 512          // thread t owns column/negative j = t

// ---------------- Kernel 0: transpose X[512][256] -> XT[256][512] ----------------
// grid (8,4), block 256. Reads and writes fully coalesced; LDS padded stride 65.
__global__ void tl_transpose(const float* __restrict__ X, float* __restrict__ XT) {
    __shared__ float tile[64][65];
    const int t  = threadIdx.x;
    const int tx = t & 63, ty = t >> 6;       // ty 0..3
    const int r0 = blockIdx.x * 64;           // row tile of X
    const int c0 = blockIdx.y * 64;           // col tile of X
    #pragma unroll
    for (int r = ty; r < 64; r += 4)
        tile[r][tx] = X[(r0 + r) * DD + c0 + tx];
    __syncthreads();
    #pragma unroll
    for (int r = ty; r < 64; r += 4)
        XT[(c0 + r) * BB + r0 + tx] = tile[tx][r];
}

// ---------------- Kernel 1: fused distances + triplet + finalize ----------------
// grid 256 x 512. ws: total f32, count u32, ticket u32.
__global__ void __launch_bounds__(NTHR)
tl_fused(const float* __restrict__ X,
         const float* __restrict__ XT,
         const int* __restrict__ labels,
         float* __restrict__ total,
         unsigned int* __restrict__ count,
         unsigned int* __restrict__ ticket,
         float* __restrict__ out) {
    __shared__ float drowL[2][520];     // [anchor][col]; slots 512.. = -1e30 sentinel
    __shared__ int   labL[BB];
    __shared__ int   plist[2][520];
    __shared__ int   pcnt[2];
    __shared__ float nsh[2];            // anchor squared norms
    __shared__ float partf[8];

    const int t   = threadIdx.x;        // 0..511 == column j
    const int ia0 = blockIdx.x * 2;
    const int ia1 = ia0 + 1;

    labL[t] = labels[t];
    if (t < 2) pcnt[t] = 0;
    if (t < 16) drowL[t >> 3][512 + (t & 7)] = -1e30f;   // sentinel pads
    __syncthreads();

    // ---- build positive lists (LDS atomics) ----
    {
        const int l0 = labL[ia0], l1 = labL[ia1];
        if (labL[t] == l0 && t != ia0) plist[0][atomicAdd(&pcnt[0], 1)] = t;
        if (labL[t] == l1 && t != ia1) plist[1][atomicAdd(&pcnt[1], 1)] = t;
    }

    // ---- phase 1: coalesced dots via XT; anchors via wave-uniform (scalar) loads ----
    float a0 = 0.f, a1 = 0.f, nn = 0.f;
    {
        const float* Xa = X + (size_t)ia0 * DD;   // uniform address -> s_load
        const float* Xb = X + (size_t)ia1 * DD;
        #pragma unroll 8
        for (int d = 0; d < DD; ++d) {
            const float b = XT[(size_t)d * BB + t];   // lanes consecutive: coalesced
            const float u = Xa[d];
            const float v = Xb[d];
            a0 = fmaf(u, b, a0);
            a1 = fmaf(v, b, a1);
            nn = fmaf(b, b, nn);
        }
    }
    if (t == ia0) nsh[0] = nn;          // ||x_ia0||^2 (diagonal thread)
    if (t == ia1) nsh[1] = nn;
    __syncthreads();

    // ---- distances for column t vs both anchors ----
    float dk0, dk1;
    {
        const float s0 = nsh[0] + nn - 2.0f * a0;
        const float s1 = nsh[1] + nn - 2.0f * a1;
        dk0 = (s0 > 0.0f) ? sqrtf(s0) : 0.0f;
        dk1 = (s1 > 0.0f) ? sqrtf(s1) : 0.0f;
        drowL[0][t] = dk0;
        drowL[1][t] = dk1;
    }
    // pad positive lists to multiple of 8 with sentinel index 512
    if (t < 8) {
        int np = pcnt[0], pad = ((np + 7) & ~7) - np;
        if (t < pad) plist[0][np + t] = 512;
    } else if (t < 16) {
        int q = t - 8;
        int np = pcnt[1], pad = ((np + 7) & ~7) - np;
        if (q < pad) plist[1][np + q] = 512;
    }
    __syncthreads();

    // ---- phase 2: thread owns negative k = t for both anchors ----
    float lsum = 0.0f;
    #pragma unroll
    for (int a = 0; a < 2; ++a) {
        const int li  = labL[ia0 + a];
        const bool neg = (labL[t] != li);
        const float dk = (a == 0) ? dk0 : dk1;
        const int npp = (pcnt[a] + 7) & ~7;
        float s = 0.0f;
        for (int p = 0; p < npp; p += 8) {
            float dj0 = drowL[a][plist[a][p + 0]];   // uniform -> LDS broadcast
            float dj1 = drowL[a][plist[a][p + 1]];
            float dj2 = drowL[a][plist[a][p + 2]];
            float dj3 = drowL[a][plist[a][p + 3]];
            float dj4 = drowL[a][plist[a][p + 4]];
            float dj5 = drowL[a][plist[a][p + 5]];
            float dj6 = drowL[a][plist[a][p + 6]];
            float dj7 = drowL[a][plist[a][p + 7]];
            s += fmaxf(dj0 - dk + TMARGIN, 0.0f);
            s += fmaxf(dj1 - dk + TMARGIN, 0.0f);
            s += fmaxf(dj2 - dk + TMARGIN, 0.0f);
            s += fmaxf(dj3 - dk + TMARGIN, 0.0f);
            s += fmaxf(dj4 - dk + TMARGIN, 0.0f);
            s += fmaxf(dj5 - dk + TMARGIN, 0.0f);
            s += fmaxf(dj6 - dk + TMARGIN, 0.0f);
            s += fmaxf(dj7 - dk + TMARGIN, 0.0f);
        }
        if (neg) lsum += s;
    }

    // ---- block reduction + global accumulate + last-block finalize ----
    #pragma unroll
    for (int o = 32; o > 0; o >>= 1) lsum += __shfl_xor(lsum, o, 64);
    if ((t & 63) == 0) partf[t >> 6] = lsum;
    __syncthreads();
    if (t == 0) {
        float bsum = 0.0f;
        #pragma unroll
        for (int w = 0; w < 8; ++w) bsum += partf[w];
        unsigned int bcnt = 0;
        #pragma unroll
        for (int a = 0; a < 2; ++a) {
            unsigned int np = (unsigned int)pcnt[a];
            bcnt += np * (unsigned int)(BB - 1 - np);
        }
        atomicAdd(total, bsum);
        atomicAdd(count, bcnt);
        __threadfence();
        unsigned int tk = atomicAdd(ticket, 1u);
        if (tk == (unsigned int)(NBLK - 1)) {   // last block finalizes
            float        tt = atomicAdd(total, 0.0f);
            unsigned int cc = atomicAdd(count, 0u);
            out[0] = (cc > 0u) ? (tt / (float)cc) : 0.0f;
        }
    }
}

extern "C" void kernel_launch(void* const* d_in, const int* in_sizes, int n_in,
                              void* d_out, int out_size, void* d_ws, size_t ws_size,
                              hipStream_t stream) {
    const float* X      = (const float*)d_in[0];   // [512,256] f32
    const int*   labels = (const int*)d_in[1];     // [512] int

    float*        total  = (float*)d_ws;
    unsigned int* count  = (unsigned int*)((char*)d_ws + 4);
    unsigned int* ticket = (unsigned int*)((char*)d_ws + 8);
    float*        XT     = (float*)((char*)d_ws + 4096);   // 512 KB, 256-aligned

    hipMemsetAsync(d_ws, 0, 12, stream);   // total/count/ticket must be 0 every call
    tl_transpose<<<dim3(8, 4), 256, 0, stream>>>(X, XT);
    tl_fused<<<NBLK, NTHR, 0, stream>>>(X, XT, labels, total, count, ticket, (float*)d_out);
}

// Round 5
// 24.842 us; speedup vs baseline: 1.5408x; 1.5408x over previous
//
#include <hip/hip_runtime.h>
#include <math.h>

#define BB 512
#define DD 256
#define TMARGIN 0.2f
#define NBLK 256          // 2 anchors per block
#define NTHR 512          // thread t owns column/negative j = t

// ---------------- Kernel 1: per-block triplet partials (2 anchors/block) ----------------
// grid 256 x 512. Writes psum[blk], pcount[blk] with plain stores — no zeroed ws needed.
__global__ void __launch_bounds__(NTHR)
tl_part(const float* __restrict__ X,
        const int* __restrict__ labels,
        float* __restrict__ psum,
        unsigned int* __restrict__ pcount) {
    __shared__ float drowL[2][520];     // [anchor][col]; slots 512.. = -1e30 sentinel
    __shared__ int   labL[BB];
    __shared__ int   plist[2][520];
    __shared__ int   pcnt[2];
    __shared__ float nsh[2];            // anchor squared norms
    __shared__ float partf[8];

    const int t   = threadIdx.x;        // 0..511 == column j
    const int ia0 = blockIdx.x * 2;
    const int ia1 = ia0 + 1;

    labL[t] = labels[t];
    if (t < 2) pcnt[t] = 0;
    if (t < 16) drowL[t >> 3][512 + (t & 7)] = -1e30f;   // sentinel pads
    __syncthreads();

    // ---- build positive lists (LDS atomics; order-nondet, fp32 sum stays within tol) ----
    {
        const int l0 = labL[ia0], l1 = labL[ia1];
        if (labL[t] == l0 && t != ia0) plist[0][atomicAdd(&pcnt[0], 1)] = t;
        if (labL[t] == l1 && t != ia1) plist[1][atomicAdd(&pcnt[1], 1)] = t;
    }

    // ---- phase 1: dot(x_a0,x_j), dot(x_a1,x_j), ||x_j||^2 for j = t (float4 row loads) ----
    float a0 = 0.f, a1 = 0.f, nn = 0.f;
    {
        const float4* xj = (const float4*)(X + (size_t)t   * DD);
        const float4* xA = (const float4*)(X + (size_t)ia0 * DD);   // block-uniform -> s_load
        const float4* xB = (const float4*)(X + (size_t)ia1 * DD);
        #pragma unroll 8
        for (int g = 0; g < DD / 4; ++g) {
            const float4 b = xj[g];
            const float4 u = xA[g];
            const float4 v = xB[g];
            a0 += u.x * b.x + u.y * b.y + u.z * b.z + u.w * b.w;
            a1 += v.x * b.x + v.y * b.y + v.z * b.z + v.w * b.w;
            nn += b.x * b.x + b.y * b.y + b.z * b.z + b.w * b.w;
        }
    }
    if (t == ia0) nsh[0] = nn;          // anchor norms from the diagonal threads
    if (t == ia1) nsh[1] = nn;
    __syncthreads();

    // ---- distances for column t vs both anchors ----
    float dk0, dk1;
    {
        const float s0 = nsh[0] + nn - 2.0f * a0;
        const float s1 = nsh[1] + nn - 2.0f * a1;
        dk0 = (s0 > 0.0f) ? sqrtf(s0) : 0.0f;
        dk1 = (s1 > 0.0f) ? sqrtf(s1) : 0.0f;
        drowL[0][t] = dk0;
        drowL[1][t] = dk1;
    }
    // pad positive lists to multiple of 8 with sentinel index 512
    if (t < 8) {
        int np = pcnt[0], pad = ((np + 7) & ~7) - np;
        if (t < pad) plist[0][np + t] = 512;
    } else if (t < 16) {
        int q = t - 8;
        int np = pcnt[1], pad = ((np + 7) & ~7) - np;
        if (q < pad) plist[1][np + q] = 512;
    }
    __syncthreads();

    // ---- phase 2: thread owns negative k = t for both anchors ----
    float lsum = 0.0f;
    #pragma unroll
    for (int a = 0; a < 2; ++a) {
        const int li   = labL[ia0 + a];
        const bool neg = (labL[t] != li);
        const float dk = (a == 0) ? dk0 : dk1;
        const int npp  = (pcnt[a] + 7) & ~7;
        float s = 0.0f;
        for (int p = 0; p < npp; p += 8) {
            float dj0 = drowL[a][plist[a][p + 0]];   // uniform -> LDS broadcast
            float dj1 = drowL[a][plist[a][p + 1]];
            float dj2 = drowL[a][plist[a][p + 2]];
            float dj3 = drowL[a][plist[a][p + 3]];
            float dj4 = drowL[a][plist[a][p + 4]];
            float dj5 = drowL[a][plist[a][p + 5]];
            float dj6 = drowL[a][plist[a][p + 6]];
            float dj7 = drowL[a][plist[a][p + 7]];
            s += fmaxf(dj0 - dk + TMARGIN, 0.0f);
            s += fmaxf(dj1 - dk + TMARGIN, 0.0f);
            s += fmaxf(dj2 - dk + TMARGIN, 0.0f);
            s += fmaxf(dj3 - dk + TMARGIN, 0.0f);
            s += fmaxf(dj4 - dk + TMARGIN, 0.0f);
            s += fmaxf(dj5 - dk + TMARGIN, 0.0f);
            s += fmaxf(dj6 - dk + TMARGIN, 0.0f);
            s += fmaxf(dj7 - dk + TMARGIN, 0.0f);
        }
        if (neg) lsum += s;
    }

    // ---- block reduction, write this block's partial to its own slot ----
    #pragma unroll
    for (int o = 32; o > 0; o >>= 1) lsum += __shfl_xor(lsum, o, 64);
    if ((t & 63) == 0) partf[t >> 6] = lsum;
    __syncthreads();
    if (t == 0) {
        float bsum = 0.0f;
        #pragma unroll
        for (int w = 0; w < 8; ++w) bsum += partf[w];
        unsigned int bcnt = 0;
        #pragma unroll
        for (int a = 0; a < 2; ++a) {
            unsigned int np = (unsigned int)pcnt[a];
            bcnt += np * (unsigned int)(BB - 1 - np);
        }
        psum[blockIdx.x]   = bsum;     // plain stores; kernel-boundary coherence
        pcount[blockIdx.x] = bcnt;
    }
}

// ---------------- Kernel 2: reduce 256 partials, finalize ----------------
// 1 block x 256 threads
__global__ void tl_reduce(const float* __restrict__ psum,
                          const unsigned int* __restrict__ pcount,
                          float* __restrict__ out) {
    __shared__ float        sf[4];
    __shared__ unsigned int sc[4];
    const int t = threadIdx.x;
    float        s = psum[t];
    unsigned int c = pcount[t];
    #pragma unroll
    for (int o = 32; o > 0; o >>= 1) {
        s += __shfl_xor(s, o, 64);
        c += __shfl_xor(c, o, 64);
    }
    if ((t & 63) == 0) { sf[t >> 6] = s; sc[t >> 6] = c; }
    __syncthreads();
    if (t == 0) {
        float        tt = sf[0] + sf[1] + sf[2] + sf[3];
        unsigned int cc = sc[0] + sc[1] + sc[2] + sc[3];
        out[0] = (cc > 0u) ? (tt / (float)cc) : 0.0f;
    }
}

extern "C" void kernel_launch(void* const* d_in, const int* in_sizes, int n_in,
                              void* d_out, int out_size, void* d_ws, size_t ws_size,
                              hipStream_t stream) {
    const float* X      = (const float*)d_in[0];   // [512,256] f32
    const int*   labels = (const int*)d_in[1];     // [512] int

    float*        psum   = (float*)d_ws;                          // 256 f32, all rewritten each call
    unsigned int* pcount = (unsigned int*)((char*)d_ws + 1024);   // 256 u32, all rewritten each call

    // NOTE: no hipMemsetAsync — every ws slot consumed is produced this call.
    tl_part<<<NBLK, NTHR, 0, stream>>>(X, labels, psum, pcount);
    tl_reduce<<<1, 256, 0, stream>>>(psum, pcount, (float*)d_out);
}